// Round 4
// baseline (1646.448 us; speedup 1.0000x reference)
//
#include <hip/hip_runtime.h>
#include <cstdint>
#include <cstddef>

#define NN 100000
#define EE 400000
#define CC 16
#define LL 16

// ---------- device helpers ----------
__device__ __forceinline__ float lrelu(float v){ return v > 0.0f ? v : 0.01f*v; }

__device__ __forceinline__ float waveSum(float v){
#pragma unroll
  for (int off = 32; off >= 1; off >>= 1) v += __shfl_xor(v, off);
  return v;
}

__device__ __forceinline__ float fma4(float4 w, float4 v, float a){
  a = fmaf(w.x, v.x, a); a = fmaf(w.y, v.y, a);
  a = fmaf(w.z, v.z, a); a = fmaf(w.w, v.w, a);
  return a;
}

// ---------- init: count degrees (int atomics only) ----------
__global__ __launch_bounds__(256) void k_count(const int* __restrict__ ei,
    int* __restrict__ cdst, int* __restrict__ call)
{
  int t = blockIdx.x*256 + threadIdx.x;
  if (t >= EE) return;
  int s = ei[t], d = ei[EE + t];
  atomicAdd(&cdst[d], 1);
  atomicAdd(&call[s], 1);
  atomicAdd(&call[d], 1);
}

// ---------- dual exclusive scan (SEG=1024/block) ----------
__device__ __forceinline__ void scan_one(const int* __restrict__ cnt,
    int* __restrict__ rp, int* __restrict__ bsums, int n, int* sd)
{
  int tid = threadIdx.x;
  int base = blockIdx.x*1024 + tid*4;
  int v0=0,v1=0,v2=0,v3=0;
  if (base+0 < n) v0 = cnt[base+0];
  if (base+1 < n) v1 = cnt[base+1];
  if (base+2 < n) v2 = cnt[base+2];
  if (base+3 < n) v3 = cnt[base+3];
  int tot = v0+v1+v2+v3;
  sd[tid] = tot; __syncthreads();
  for (int off=1; off<256; off<<=1){
    int add = (tid>=off) ? sd[tid-off] : 0;
    __syncthreads();
    sd[tid] += add;
    __syncthreads();
  }
  int excl = sd[tid] - tot;
  if (base+0 < n) rp[base+0] = excl;
  if (base+1 < n) rp[base+1] = excl+v0;
  if (base+2 < n) rp[base+2] = excl+v0+v1;
  if (base+3 < n) rp[base+3] = excl+v0+v1+v2;
  if (tid==255) bsums[blockIdx.x] = sd[255];
  __syncthreads();
}

__global__ __launch_bounds__(256) void k_scan1(const int* __restrict__ ca,
    int* __restrict__ rpa, int* __restrict__ bsa,
    const int* __restrict__ cb, int* __restrict__ rpb, int* __restrict__ bsb, int n)
{
  __shared__ int sd[256];
  scan_one(ca, rpa, bsa, n, sd);
  scan_one(cb, rpb, bsb, n, sd);
}

__device__ __forceinline__ void scan2_one(const int* __restrict__ bsums,
    int* __restrict__ boff, int nseg, int* sd)
{
  int tid = threadIdx.x;
  int v = (tid < nseg) ? bsums[tid] : 0;
  sd[tid] = v; __syncthreads();
  for (int off=1; off<256; off<<=1){
    int add = (tid>=off) ? sd[tid-off] : 0;
    __syncthreads();
    sd[tid] += add;
    __syncthreads();
  }
  if (tid < nseg) boff[tid] = sd[tid] - v;
  __syncthreads();
}

__global__ __launch_bounds__(256) void k_scan2(const int* __restrict__ bsa,
    int* __restrict__ boffa, const int* __restrict__ bsb, int* __restrict__ boffb, int nseg)
{
  __shared__ int sd[256];
  scan2_one(bsa, boffa, nseg, sd);
  scan2_one(bsb, boffb, nseg, sd);
}

__global__ __launch_bounds__(256) void k_scan3(
    int* __restrict__ rpa, int* __restrict__ cura, const int* __restrict__ boffa, int totala,
    int* __restrict__ rpb, int* __restrict__ curb, const int* __restrict__ boffb, int totalb, int n)
{
  int adda = boffa[blockIdx.x];
  int addb = boffb[blockIdx.x];
  int base = blockIdx.x*1024 + threadIdx.x*4;
#pragma unroll
  for (int i=0;i<4;i++){
    if (base+i < n){
      int va = rpa[base+i] + adda; rpa[base+i] = va; cura[base+i] = va;
      int vb = rpb[base+i] + addb; rpb[base+i] = vb; curb[base+i] = vb;
    }
  }
  if (blockIdx.x==0 && threadIdx.x==0){ rpa[n] = totala; rpb[n] = totalb; }
}

// ---------- fill: dst-sorted (src,dst) pairs + all-CSR edge list ----------
__global__ __launch_bounds__(256) void k_fill(const int* __restrict__ ei,
    int* __restrict__ cur, int2* __restrict__ sd,
    int* __restrict__ cur_all, int* __restrict__ list_all)
{
  int t = blockIdx.x*256 + threadIdx.x;
  if (t >= EE) return;
  int s = ei[t], d = ei[EE + t];
  int p = atomicAdd(&cur[d], 1);
  sd[p] = make_int2(s, d);
  int pa = atomicAdd(&cur_all[s], 1);
  list_all[pa] = t;
  int pb = atomicAdd(&cur_all[d], 1);
  list_all[pb] = t;
}

// ---------- x0 = mean of incident edge features; invdeg = 1/clip(deg_in,1) ----------
__global__ __launch_bounds__(256) void k_gather0(const float* __restrict__ ef,
    const int* __restrict__ rp_all, const int* __restrict__ list_all,
    const int* __restrict__ rp, float* __restrict__ x0, float* __restrict__ invdeg)
{
  int t = blockIdx.x*256 + threadIdx.x;
  if (t >= NN*CC) return;
  int n = t >> 4, c = t & 15;
  int beg = rp_all[n], end = rp_all[n+1];
  float acc = 0.0f;
  for (int i=beg; i<end; i++){
    acc += ef[(size_t)list_all[i]*CC + c];
  }
  float dg = fmaxf((float)(end-beg), 1.0f);
  x0[t] = acc / dg;
  if (c == 0){
    int di = rp[n+1] - rp[n];
    invdeg[n] = 1.0f / fmaxf((float)di, 1.0f);
  }
}

// ---------- per-layer: BN stats only (no m store) ----------
__global__ __launch_bounds__(256) void k_stat(const float* __restrict__ x,
    const int2* __restrict__ sd,
    const float* __restrict__ W, const float* __restrict__ b,
    double* __restrict__ st)
{
  __shared__ float sW[512];
  __shared__ float sb16[16];
  __shared__ float sredS[64], sredQ[64];
  for (int i=threadIdx.x; i<512; i+=256) sW[i] = W[i];
  if (threadIdx.x < 16) sb16[threadIdx.x] = b[threadIdx.x];
  __syncthreads();

  int t = blockIdx.x*256 + threadIdx.x;
  int e0 = 2*t, e1 = 2*t+1;
  bool val = (e1 < EE);
  float acc0[16], acc1[16];
  if (val){
    int2 p0 = sd[e0], p1 = sd[e1];
    float4 xc0[8], xc1[8];
    const float4* p;
    p = (const float4*)(x + (size_t)p0.y*CC); xc0[0]=p[0]; xc0[1]=p[1]; xc0[2]=p[2]; xc0[3]=p[3];
    p = (const float4*)(x + (size_t)p0.x*CC); xc0[4]=p[0]; xc0[5]=p[1]; xc0[6]=p[2]; xc0[7]=p[3];
    p = (const float4*)(x + (size_t)p1.y*CC); xc1[0]=p[0]; xc1[1]=p[1]; xc1[2]=p[2]; xc1[3]=p[3];
    p = (const float4*)(x + (size_t)p1.x*CC); xc1[4]=p[0]; xc1[5]=p[1]; xc1[6]=p[2]; xc1[7]=p[3];
#pragma unroll
    for (int c=0;c<CC;c++){
      const float4* wr = (const float4*)(sW + c*32);
      float a0 = sb16[c], a1 = sb16[c];
#pragma unroll
      for (int q=0;q<8;q++){
        float4 w = wr[q];
        a0 = fma4(w, xc0[q], a0);
        a1 = fma4(w, xc1[q], a1);
      }
      acc0[c]=a0; acc1[c]=a1;
    }
  } else {
#pragma unroll
    for (int c=0;c<CC;c++){ acc0[c]=0.0f; acc1[c]=0.0f; }
  }

  int lane = threadIdx.x & 63, w = threadIdx.x >> 6;
#pragma unroll
  for (int c=0;c<CC;c++){
    float rs = acc0[c] + acc1[c];
    float rq = acc0[c]*acc0[c] + acc1[c]*acc1[c];
    rs = waveSum(rs); rq = waveSum(rq);
    if (lane == 0){ sredS[w*16+c] = rs; sredQ[w*16+c] = rq; }
  }
  __syncthreads();
  if (threadIdx.x < 16){
    int c = threadIdx.x;
    float tot = sredS[c] + sredS[16+c] + sredS[32+c] + sredS[48+c];
    unsafeAtomicAdd(&st[c], (double)tot);
  } else if (threadIdx.x < 32){
    int c = threadIdx.x - 16;
    float tot = sredQ[c] + sredQ[16+c] + sredQ[32+c] + sredQ[48+c];
    unsafeAtomicAdd(&st[16+c], (double)tot);
  }
}

// ---------- per-layer: recompute m per in-edge, BN+leaky, segment-mean ----------
__global__ __launch_bounds__(256) void k_node(const float* __restrict__ x,
    const int2* __restrict__ sd, const int* __restrict__ rp,
    const float* __restrict__ invdeg, const double* __restrict__ st,
    const float* __restrict__ W, const float* __restrict__ b,
    const float* __restrict__ g, const float* __restrict__ bt,
    float* __restrict__ xout)
{
  __shared__ float sA[16], sB[16];
  if (threadIdx.x < 16){
    int c = threadIdx.x;
    double mu  = st[c] * (1.0/EE);
    double var = st[16+c] * (1.0/EE) - mu*mu;
    float sc = rsqrtf((float)var + 1e-5f);
    float A = sc * g[c];
    sA[c] = A; sB[c] = bt[c] - (float)mu * A;
  }
  __syncthreads();
  int t = blockIdx.x*256 + threadIdx.x;
  int n = t >> 4, c = t & 15;
  if (n >= NN) return;
  // W row c: left half (dst), right half (src)
  const float4* wrow = (const float4*)(W + c*32);
  float4 wl0 = wrow[0], wl1 = wrow[1], wl2 = wrow[2], wl3 = wrow[3];
  float4 wr0 = wrow[4], wr1 = wrow[5], wr2 = wrow[6], wr3 = wrow[7];
  // y = b[c] + W_left . x[n]
  const float4* xn = (const float4*)(x + (size_t)n*CC);
  float y = b[c];
  y = fma4(wl0, xn[0], y); y = fma4(wl1, xn[1], y);
  y = fma4(wl2, xn[2], y); y = fma4(wl3, xn[3], y);

  float A = sA[c], B = sB[c];
  int beg = rp[n], end = rp[n+1];
  float acc = 0.0f;
  for (int i=beg; i<end; i++){
    int s = sd[i].x;
    const float4* xs = (const float4*)(x + (size_t)s*CC);
    float m = y;
    m = fma4(wr0, xs[0], m); m = fma4(wr1, xs[1], m);
    m = fma4(wr2, xs[2], m); m = fma4(wr3, xs[3], m);
    acc += lrelu(fmaf(A, m, B));
  }
  xout[t] = acc * invdeg[n];
}

// ---------- final stage 1: BN stats over 2E rows (both orientations) ----------
__global__ __launch_bounds__(256) void k_final1(const float* __restrict__ x,
    const int* __restrict__ ei, const float* __restrict__ W, const float* __restrict__ b,
    double* __restrict__ st)
{
  __shared__ float sW[512];
  __shared__ float sb16[16];
  __shared__ float sredS[64], sredQ[64];
  for (int i=threadIdx.x; i<512; i+=256) sW[i] = W[i];
  if (threadIdx.x < 16) sb16[threadIdx.x] = b[threadIdx.x];
  __syncthreads();

  int t = blockIdx.x*256 + threadIdx.x;
  bool val = (t < EE);
  float af[16], ab[16];
  if (val){
    int s = ei[t], d = ei[EE+t];
    float4 xs[4], xd[4];
    const float4* p;
    p = (const float4*)(x + (size_t)s*CC); xs[0]=p[0]; xs[1]=p[1]; xs[2]=p[2]; xs[3]=p[3];
    p = (const float4*)(x + (size_t)d*CC); xd[0]=p[0]; xd[1]=p[1]; xd[2]=p[2]; xd[3]=p[3];
#pragma unroll
    for (int c=0;c<CC;c++){
      const float4* wr = (const float4*)(sW + c*32);
      float f = sb16[c], g_ = sb16[c];
#pragma unroll
      for (int q=0;q<4;q++){ float4 w = wr[q];   f = fma4(w, xs[q], f);  g_ = fma4(w, xd[q], g_); }
#pragma unroll
      for (int q=0;q<4;q++){ float4 w = wr[4+q]; f = fma4(w, xd[q], f);  g_ = fma4(w, xs[q], g_); }
      af[c]=f; ab[c]=g_;
    }
  } else {
#pragma unroll
    for (int c=0;c<CC;c++){ af[c]=0.0f; ab[c]=0.0f; }
  }

  int lane = threadIdx.x & 63, w = threadIdx.x >> 6;
#pragma unroll
  for (int c=0;c<CC;c++){
    float rs = af[c] + ab[c];
    float rq = af[c]*af[c] + ab[c]*ab[c];
    rs = waveSum(rs); rq = waveSum(rq);
    if (lane == 0){ sredS[w*16+c] = rs; sredQ[w*16+c] = rq; }
  }
  __syncthreads();
  if (threadIdx.x < 16){
    int c = threadIdx.x;
    float tot = sredS[c] + sredS[16+c] + sredS[32+c] + sredS[48+c];
    unsafeAtomicAdd(&st[c], (double)tot);
  } else if (threadIdx.x < 32){
    int c = threadIdx.x - 16;
    float tot = sredQ[c] + sredQ[16+c] + sredQ[32+c] + sredQ[48+c];
    unsafeAtomicAdd(&st[16+c], (double)tot);
  }
}

// ---------- final stage 2: recompute, BN+leaky, edge_out + loss accumulation ----------
__global__ __launch_bounds__(256) void k_final2(const float* __restrict__ x,
    const int* __restrict__ ei, const float* __restrict__ W, const float* __restrict__ b,
    const double* __restrict__ st, const float* __restrict__ g, const float* __restrict__ bt,
    float* __restrict__ out, double* __restrict__ loss)
{
  __shared__ float sW[512];
  __shared__ float sb16[16];
  __shared__ float sA[16], sB[16];
  __shared__ float sl[4];
  for (int i=threadIdx.x; i<512; i+=256) sW[i] = W[i];
  if (threadIdx.x < 16){
    int c = threadIdx.x;
    sb16[c] = b[c];
    double mu  = st[c] * (1.0/(2.0*EE));
    double var = st[16+c] * (1.0/(2.0*EE)) - mu*mu;
    float sc = rsqrtf((float)var + 1e-5f);
    float A = sc * g[c];
    sA[c] = A; sB[c] = bt[c] - (float)mu * A;
  }
  __syncthreads();

  int t = blockIdx.x*256 + threadIdx.x;
  bool val = (t < EE);
  float lsum = 0.0f;
  if (val){
    int s = ei[t], d = ei[EE+t];
    float4 xs[4], xd[4];
    const float4* p;
    p = (const float4*)(x + (size_t)s*CC); xs[0]=p[0]; xs[1]=p[1]; xs[2]=p[2]; xs[3]=p[3];
    p = (const float4*)(x + (size_t)d*CC); xd[0]=p[0]; xd[1]=p[1]; xd[2]=p[2]; xd[3]=p[3];
    float fo[16];
#pragma unroll
    for (int c=0;c<CC;c++){
      const float4* wr = (const float4*)(sW + c*32);
      float f = sb16[c], g_ = sb16[c];
#pragma unroll
      for (int q=0;q<4;q++){ float4 w = wr[q];   f = fma4(w, xs[q], f);  g_ = fma4(w, xd[q], g_); }
#pragma unroll
      for (int q=0;q<4;q++){ float4 w = wr[4+q]; f = fma4(w, xd[q], f);  g_ = fma4(w, xs[q], g_); }
      float efv = lrelu(fmaf(sA[c], f,  sB[c]));
      float ebv = lrelu(fmaf(sA[c], g_, sB[c]));
      fo[c] = 0.5f*(efv + ebv);
      float dlt = efv - ebv;
      lsum = fmaf(dlt, dlt, lsum);
    }
    float4* po = (float4*)(out + (size_t)t*CC);
    po[0]=make_float4(fo[0],fo[1],fo[2],fo[3]);
    po[1]=make_float4(fo[4],fo[5],fo[6],fo[7]);
    po[2]=make_float4(fo[8],fo[9],fo[10],fo[11]);
    po[3]=make_float4(fo[12],fo[13],fo[14],fo[15]);
  }
  lsum = waveSum(lsum);
  int lane = threadIdx.x & 63, w = threadIdx.x >> 6;
  if (lane == 0) sl[w] = lsum;
  __syncthreads();
  if (threadIdx.x == 0)
    unsafeAtomicAdd(loss, (double)(sl[0]+sl[1]+sl[2]+sl[3]));
}

__global__ void k_final3(float* __restrict__ out, const double* __restrict__ loss)
{
  out[(size_t)EE*CC] = (float)(loss[0] * (1.0/((double)EE*CC)));
}

// ---------- host ----------
extern "C" void kernel_launch(void* const* d_in, const int* in_sizes, int n_in,
                              void* d_out, int out_size, void* d_ws, size_t ws_size,
                              hipStream_t stream)
{
  (void)in_sizes; (void)n_in; (void)out_size; (void)ws_size;
  const float* ef  = (const float*)d_in[0];
  const int*   ei  = (const int*)d_in[1];
  // d_in[2] = angles (unused by reference forward)
  const float* Wn  = (const float*)d_in[3];
  const float* bn  = (const float*)d_in[4];
  const float* gn  = (const float*)d_in[5];
  const float* btn = (const float*)d_in[6];
  const float* We  = (const float*)d_in[7];
  const float* be  = (const float*)d_in[8];
  const float* ge  = (const float*)d_in[9];
  const float* bte = (const float*)d_in[10];
  float* out = (float*)d_out;
  char* ws = (char*)d_ws;

  size_t off = 0;
  auto alloc = [&](size_t bytes)->size_t{
    size_t r = off; off = (off + bytes + 255) & ~(size_t)255; return r;
  };
  size_t o_xa     = alloc((size_t)NN*CC*4);
  size_t o_xb     = alloc((size_t)NN*CC*4);
  size_t o_cdst   = alloc((size_t)NN*4);
  size_t o_call   = alloc((size_t)NN*4);
  size_t o_rp     = alloc((size_t)(NN+1)*4);
  size_t o_rpall  = alloc((size_t)(NN+1)*4);
  size_t o_cur    = alloc((size_t)NN*4);
  size_t o_curall = alloc((size_t)NN*4);
  size_t o_sd     = alloc((size_t)EE*8);
  size_t o_listall= alloc((size_t)2*EE*4);
  size_t o_bsum   = alloc(512);
  size_t o_bsum2  = alloc(512);
  size_t o_boff   = alloc(512);
  size_t o_boff2  = alloc(512);
  size_t o_stats  = alloc(545*8);   // 17 slots * 32 doubles + 1 loss double
  size_t o_invdeg = alloc((size_t)NN*4);

  float*  x_a     = (float*)(ws + o_xa);
  float*  x_b     = (float*)(ws + o_xb);
  int*    cdst    = (int*)(ws + o_cdst);
  int*    call_   = (int*)(ws + o_call);
  int*    rp      = (int*)(ws + o_rp);
  int*    rp_all  = (int*)(ws + o_rpall);
  int*    cur     = (int*)(ws + o_cur);
  int*    cur_all = (int*)(ws + o_curall);
  int2*   sd      = (int2*)(ws + o_sd);
  int*    list_all= (int*)(ws + o_listall);
  int*    bsum    = (int*)(ws + o_bsum);
  int*    bsum2   = (int*)(ws + o_bsum2);
  int*    boff    = (int*)(ws + o_boff);
  int*    boff2   = (int*)(ws + o_boff2);
  double* stats   = (double*)(ws + o_stats);
  double* lossd   = stats + 17*32;   // index 544
  float*  invdeg  = (float*)(ws + o_invdeg);

  const int GB_E  = (EE + 255)/256;       // 1563
  const int GB_E2 = (EE/2 + 255)/256;     // 782
  const int GB_NC = (NN*CC + 255)/256;    // 6250
  const int NSEG  = (NN + 1023)/1024;     // 98

  hipMemsetAsync(cdst, 0, (size_t)NN*4, stream);
  hipMemsetAsync(call_, 0, (size_t)NN*4, stream);
  hipMemsetAsync(stats, 0, 545*8, stream);

  k_count<<<GB_E, 256, 0, stream>>>(ei, cdst, call_);
  // both CSRs scanned in one pass-chain
  k_scan1<<<NSEG, 256, 0, stream>>>(cdst, rp, bsum, call_, rp_all, bsum2, NN);
  k_scan2<<<1, 256, 0, stream>>>(bsum, boff, bsum2, boff2, NSEG);
  k_scan3<<<NSEG, 256, 0, stream>>>(rp, cur, boff, EE, rp_all, cur_all, boff2, 2*EE, NN);
  // fill: dst-sorted (src,dst) pairs + all-CSR list
  k_fill<<<GB_E, 256, 0, stream>>>(ei, cur, sd, cur_all, list_all);
  // initial node features (gather-mean) + invdeg
  k_gather0<<<GB_NC, 256, 0, stream>>>(ef, rp_all, list_all, rp, x_a, invdeg);

  const float* xc = x_a;
  float* xn = x_b;
  for (int l = 0; l < LL; ++l){
    double* st = stats + (size_t)l*32;
    const float* Wl = Wn + (size_t)l*CC*2*CC;
    const float* bl = bn + (size_t)l*CC;
    k_stat<<<GB_E2, 256, 0, stream>>>(xc, sd, Wl, bl, st);
    k_node<<<GB_NC, 256, 0, stream>>>(xc, sd, rp, invdeg, st, Wl, bl,
                                      gn + (size_t)l*CC, btn + (size_t)l*CC, xn);
    float* tmp = (float*)xc; xc = xn; xn = tmp;
  }

  double* stF = stats + 16*32;
  k_final1<<<GB_E, 256, 0, stream>>>(xc, ei, We, be, stF);
  k_final2<<<GB_E, 256, 0, stream>>>(xc, ei, We, be, stF, ge, bte, out, lossd);
  k_final3<<<1, 1, 0, stream>>>(out, lossd);
}

// Round 6
// 865.423 us; speedup vs baseline: 1.9025x; 1.9025x over previous
//
#include <hip/hip_runtime.h>
#include <hip/hip_fp16.h>
#include <cstdint>
#include <cstddef>

#define NN 100000
#define EE 400000
#define CC 16
#define LL 16
#define NB 8   // stats atomic buckets

typedef unsigned int uint;

// ---------- device helpers ----------
__device__ __forceinline__ float lrelu(float v){ return v > 0.0f ? v : 0.01f*v; }

__device__ __forceinline__ float waveSum(float v){
#pragma unroll
  for (int off = 32; off >= 1; off >>= 1) v += __shfl_xor(v, off);
  return v;
}

__device__ __forceinline__ float fma4(float4 w, float4 v, float a){
  a = fmaf(w.x, v.x, a); a = fmaf(w.y, v.y, a);
  a = fmaf(w.z, v.z, a); a = fmaf(w.w, v.w, a);
  return a;
}

// pack two floats into one uint as half2 (lo = first arg)
__device__ __forceinline__ uint pack_h2(float a, float b){
  __half2 h = __floats2half2_rn(a, b);
  return *reinterpret_cast<uint*>(&h);
}
__device__ __forceinline__ float2 unpack_h2(uint v){
  __half2 h = *reinterpret_cast<__half2*>(&v);
  return __half22float2(h);
}

// ---------- init: count degrees (int atomics only) ----------
__global__ __launch_bounds__(256) void k_count(const int* __restrict__ ei,
    int* __restrict__ cdst, int* __restrict__ call)
{
  int t = blockIdx.x*256 + threadIdx.x;
  if (t >= EE) return;
  int s = ei[t], d = ei[EE + t];
  atomicAdd(&cdst[d], 1);
  atomicAdd(&call[s], 1);
  atomicAdd(&call[d], 1);
}

// ---------- dual exclusive scan (SEG=1024/block) ----------
__device__ __forceinline__ void scan_one(const int* __restrict__ cnt,
    int* __restrict__ rp, int* __restrict__ bsums, int n, int* sd)
{
  int tid = threadIdx.x;
  int base = blockIdx.x*1024 + tid*4;
  int v0=0,v1=0,v2=0,v3=0;
  if (base+0 < n) v0 = cnt[base+0];
  if (base+1 < n) v1 = cnt[base+1];
  if (base+2 < n) v2 = cnt[base+2];
  if (base+3 < n) v3 = cnt[base+3];
  int tot = v0+v1+v2+v3;
  sd[tid] = tot; __syncthreads();
  for (int off=1; off<256; off<<=1){
    int add = (tid>=off) ? sd[tid-off] : 0;
    __syncthreads();
    sd[tid] += add;
    __syncthreads();
  }
  int excl = sd[tid] - tot;
  if (base+0 < n) rp[base+0] = excl;
  if (base+1 < n) rp[base+1] = excl+v0;
  if (base+2 < n) rp[base+2] = excl+v0+v1;
  if (base+3 < n) rp[base+3] = excl+v0+v1+v2;
  if (tid==255) bsums[blockIdx.x] = sd[255];
  __syncthreads();
}

__global__ __launch_bounds__(256) void k_scan1(const int* __restrict__ ca,
    int* __restrict__ rpa, int* __restrict__ bsa,
    const int* __restrict__ cb, int* __restrict__ rpb, int* __restrict__ bsb, int n)
{
  __shared__ int sd[256];
  scan_one(ca, rpa, bsa, n, sd);
  scan_one(cb, rpb, bsb, n, sd);
}

__device__ __forceinline__ void scan2_one(const int* __restrict__ bsums,
    int* __restrict__ boff, int nseg, int* sd)
{
  int tid = threadIdx.x;
  int v = (tid < nseg) ? bsums[tid] : 0;
  sd[tid] = v; __syncthreads();
  for (int off=1; off<256; off<<=1){
    int add = (tid>=off) ? sd[tid-off] : 0;
    __syncthreads();
    sd[tid] += add;
    __syncthreads();
  }
  if (tid < nseg) boff[tid] = sd[tid] - v;
  __syncthreads();
}

__global__ __launch_bounds__(256) void k_scan2(const int* __restrict__ bsa,
    int* __restrict__ boffa, const int* __restrict__ bsb, int* __restrict__ boffb, int nseg)
{
  __shared__ int sd[256];
  scan2_one(bsa, boffa, nseg, sd);
  scan2_one(bsb, boffb, nseg, sd);
}

__global__ __launch_bounds__(256) void k_scan3(
    int* __restrict__ rpa, int* __restrict__ cura, const int* __restrict__ boffa, int totala,
    int* __restrict__ rpb, int* __restrict__ curb, const int* __restrict__ boffb, int totalb, int n)
{
  int adda = boffa[blockIdx.x];
  int addb = boffb[blockIdx.x];
  int base = blockIdx.x*1024 + threadIdx.x*4;
#pragma unroll
  for (int i=0;i<4;i++){
    if (base+i < n){
      int va = rpa[base+i] + adda; rpa[base+i] = va; cura[base+i] = va;
      int vb = rpb[base+i] + addb; rpb[base+i] = vb; curb[base+i] = vb;
    }
  }
  if (blockIdx.x==0 && threadIdx.x==0){ rpa[n] = totala; rpb[n] = totalb; }
}

// ---------- fill: dst-sorted (src,dst) pairs + all-CSR edge list ----------
__global__ __launch_bounds__(256) void k_fill(const int* __restrict__ ei,
    int* __restrict__ cur, int2* __restrict__ sd,
    int* __restrict__ cur_all, int* __restrict__ list_all)
{
  int t = blockIdx.x*256 + threadIdx.x;
  if (t >= EE) return;
  int s = ei[t], d = ei[EE + t];
  int p = atomicAdd(&cur[d], 1);
  sd[p] = make_int2(s, d);
  int pa = atomicAdd(&cur_all[s], 1);
  list_all[pa] = t;
  int pb = atomicAdd(&cur_all[d], 1);
  list_all[pb] = t;
}

// ---------- x0 = mean of incident edge features; invdeg = 1/clip(deg_in,1) ----------
__global__ __launch_bounds__(256) void k_gather0(const float* __restrict__ ef,
    const int* __restrict__ rp_all, const int* __restrict__ list_all,
    const int* __restrict__ rp, float* __restrict__ x0, float* __restrict__ invdeg)
{
  int t = blockIdx.x*256 + threadIdx.x;
  if (t >= NN*CC) return;
  int n = t >> 4, c = t & 15;
  int beg = rp_all[n], end = rp_all[n+1];
  float acc = 0.0f;
  for (int i=beg; i<end; i++){
    acc += ef[(size_t)list_all[i]*CC + c];
  }
  float dg = fmaxf((float)(end-beg), 1.0f);
  x0[t] = acc / dg;
  if (c == 0){
    int di = rp[n+1] - rp[n];
    invdeg[n] = 1.0f / fmaxf((float)di, 1.0f);
  }
}

// ---------- per-layer: m = W @ cat(x[dst],x[src]) + b -> fp16 store + BN stats ----------
__global__ __launch_bounds__(256) void k_edge(const float* __restrict__ x,
    const int2* __restrict__ sd,
    const float* __restrict__ W, const float* __restrict__ b,
    uint* __restrict__ mh, double* __restrict__ st)
{
  __shared__ float sW[512];
  __shared__ float sb16[16];
  __shared__ float sredS[64], sredQ[64];
  for (int i=threadIdx.x; i<512; i+=256) sW[i] = W[i];
  if (threadIdx.x < 16) sb16[threadIdx.x] = b[threadIdx.x];
  __syncthreads();

  int t = blockIdx.x*256 + threadIdx.x;
  int e0 = 2*t, e1 = 2*t+1;
  bool val = (e1 < EE);
  float acc0[16], acc1[16];
  if (val){
    int2 p0 = sd[e0], p1 = sd[e1];
    float4 xc0[8], xc1[8];
    const float4* p;
    p = (const float4*)(x + (size_t)p0.y*CC); xc0[0]=p[0]; xc0[1]=p[1]; xc0[2]=p[2]; xc0[3]=p[3];
    p = (const float4*)(x + (size_t)p0.x*CC); xc0[4]=p[0]; xc0[5]=p[1]; xc0[6]=p[2]; xc0[7]=p[3];
    p = (const float4*)(x + (size_t)p1.y*CC); xc1[0]=p[0]; xc1[1]=p[1]; xc1[2]=p[2]; xc1[3]=p[3];
    p = (const float4*)(x + (size_t)p1.x*CC); xc1[4]=p[0]; xc1[5]=p[1]; xc1[6]=p[2]; xc1[7]=p[3];
#pragma unroll
    for (int c=0;c<CC;c++){
      const float4* wr = (const float4*)(sW + c*32);
      float a0 = sb16[c], a1 = sb16[c];
#pragma unroll
      for (int q=0;q<8;q++){
        float4 w = wr[q];
        a0 = fma4(w, xc0[q], a0);
        a1 = fma4(w, xc1[q], a1);
      }
      acc0[c]=a0; acc1[c]=a1;
    }
    // pack to fp16x2 and store (exact stats are taken from f32 accs below)
    uint w0[8], w1[8];
#pragma unroll
    for (int q=0;q<8;q++){
      w0[q] = pack_h2(acc0[2*q], acc0[2*q+1]);
      w1[q] = pack_h2(acc1[2*q], acc1[2*q+1]);
    }
    uint4* po0 = (uint4*)(mh + (size_t)e0*8);
    po0[0] = make_uint4(w0[0],w0[1],w0[2],w0[3]);
    po0[1] = make_uint4(w0[4],w0[5],w0[6],w0[7]);
    uint4* po1 = (uint4*)(mh + (size_t)e1*8);
    po1[0] = make_uint4(w1[0],w1[1],w1[2],w1[3]);
    po1[1] = make_uint4(w1[4],w1[5],w1[6],w1[7]);
  } else {
#pragma unroll
    for (int c=0;c<CC;c++){ acc0[c]=0.0f; acc1[c]=0.0f; }
  }

  int lane = threadIdx.x & 63, w = threadIdx.x >> 6;
#pragma unroll
  for (int c=0;c<CC;c++){
    float rs = acc0[c] + acc1[c];
    float rq = acc0[c]*acc0[c] + acc1[c]*acc1[c];
    rs = waveSum(rs); rq = waveSum(rq);
    if (lane == 0){ sredS[w*16+c] = rs; sredQ[w*16+c] = rq; }
  }
  __syncthreads();
  double* stb = st + (size_t)(blockIdx.x & (NB-1))*32;
  if (threadIdx.x < 16){
    int c = threadIdx.x;
    float tot = sredS[c] + sredS[16+c] + sredS[32+c] + sredS[48+c];
    unsafeAtomicAdd(&stb[c], (double)tot);
  } else if (threadIdx.x < 32){
    int c = threadIdx.x - 16;
    float tot = sredQ[c] + sredQ[16+c] + sredQ[32+c] + sredQ[48+c];
    unsafeAtomicAdd(&stb[16+c], (double)tot);
  }
}

// ---------- per-layer: finalize BN, leaky, contiguous segment-mean by dst ----------
// 8 threads per node, 2 channels per thread (fp16x2 loads)
__global__ __launch_bounds__(256) void k_node(const uint* __restrict__ mh,
    const int* __restrict__ rp,
    const float* __restrict__ invdeg, const double* __restrict__ st,
    const float* __restrict__ g, const float* __restrict__ bt,
    float* __restrict__ xout)
{
  __shared__ float sA[16], sB[16];
  if (threadIdx.x < 16){
    int c = threadIdx.x;
    double S = 0.0, Q = 0.0;
#pragma unroll
    for (int k=0;k<NB;k++){ S += st[k*32 + c]; Q += st[k*32 + 16 + c]; }
    double mu  = S * (1.0/EE);
    double var = Q * (1.0/EE) - mu*mu;
    float sc = rsqrtf((float)var + 1e-5f);
    float A = sc * g[c];
    sA[c] = A; sB[c] = bt[c] - (float)mu * A;
  }
  __syncthreads();
  int t = blockIdx.x*256 + threadIdx.x;
  int n = t >> 3, cp = t & 7;
  if (n >= NN) return;
  float A0 = sA[2*cp], B0 = sB[2*cp];
  float A1 = sA[2*cp+1], B1 = sB[2*cp+1];
  int beg = rp[n], end = rp[n+1];
  float a0 = 0.0f, a1 = 0.0f;
  for (int i=beg; i<end; i++){
    float2 v = unpack_h2(mh[(size_t)i*8 + cp]);
    a0 += lrelu(fmaf(A0, v.x, B0));
    a1 += lrelu(fmaf(A1, v.y, B1));
  }
  float iv = invdeg[n];
  float2* po = (float2*)(xout + (size_t)n*CC + 2*cp);
  *po = make_float2(a0*iv, a1*iv);
}

// ---------- final stage 1: BN stats over 2E rows (both orientations) ----------
__global__ __launch_bounds__(256) void k_final1(const float* __restrict__ x,
    const int* __restrict__ ei, const float* __restrict__ W, const float* __restrict__ b,
    double* __restrict__ st)
{
  __shared__ float sW[512];
  __shared__ float sb16[16];
  __shared__ float sredS[64], sredQ[64];
  for (int i=threadIdx.x; i<512; i+=256) sW[i] = W[i];
  if (threadIdx.x < 16) sb16[threadIdx.x] = b[threadIdx.x];
  __syncthreads();

  int t = blockIdx.x*256 + threadIdx.x;
  bool val = (t < EE);
  float af[16], ab[16];
  if (val){
    int s = ei[t], d = ei[EE+t];
    float4 xs[4], xd[4];
    const float4* p;
    p = (const float4*)(x + (size_t)s*CC); xs[0]=p[0]; xs[1]=p[1]; xs[2]=p[2]; xs[3]=p[3];
    p = (const float4*)(x + (size_t)d*CC); xd[0]=p[0]; xd[1]=p[1]; xd[2]=p[2]; xd[3]=p[3];
#pragma unroll
    for (int c=0;c<CC;c++){
      const float4* wr = (const float4*)(sW + c*32);
      float f = sb16[c], g_ = sb16[c];
#pragma unroll
      for (int q=0;q<4;q++){ float4 w = wr[q];   f = fma4(w, xs[q], f);  g_ = fma4(w, xd[q], g_); }
#pragma unroll
      for (int q=0;q<4;q++){ float4 w = wr[4+q]; f = fma4(w, xd[q], f);  g_ = fma4(w, xs[q], g_); }
      af[c]=f; ab[c]=g_;
    }
  } else {
#pragma unroll
    for (int c=0;c<CC;c++){ af[c]=0.0f; ab[c]=0.0f; }
  }

  int lane = threadIdx.x & 63, w = threadIdx.x >> 6;
#pragma unroll
  for (int c=0;c<CC;c++){
    float rs = af[c] + ab[c];
    float rq = af[c]*af[c] + ab[c]*ab[c];
    rs = waveSum(rs); rq = waveSum(rq);
    if (lane == 0){ sredS[w*16+c] = rs; sredQ[w*16+c] = rq; }
  }
  __syncthreads();
  double* stb = st + (size_t)(blockIdx.x & (NB-1))*32;
  if (threadIdx.x < 16){
    int c = threadIdx.x;
    float tot = sredS[c] + sredS[16+c] + sredS[32+c] + sredS[48+c];
    unsafeAtomicAdd(&stb[c], (double)tot);
  } else if (threadIdx.x < 32){
    int c = threadIdx.x - 16;
    float tot = sredQ[c] + sredQ[16+c] + sredQ[32+c] + sredQ[48+c];
    unsafeAtomicAdd(&stb[16+c], (double)tot);
  }
}

// ---------- final stage 2: recompute, BN+leaky, edge_out + loss accumulation ----------
__global__ __launch_bounds__(256) void k_final2(const float* __restrict__ x,
    const int* __restrict__ ei, const float* __restrict__ W, const float* __restrict__ b,
    const double* __restrict__ st, const float* __restrict__ g, const float* __restrict__ bt,
    float* __restrict__ out, double* __restrict__ loss)
{
  __shared__ float sW[512];
  __shared__ float sb16[16];
  __shared__ float sA[16], sB[16];
  __shared__ float sl[4];
  for (int i=threadIdx.x; i<512; i+=256) sW[i] = W[i];
  if (threadIdx.x < 16){
    int c = threadIdx.x;
    sb16[c] = b[c];
    double S = 0.0, Q = 0.0;
#pragma unroll
    for (int k=0;k<NB;k++){ S += st[k*32 + c]; Q += st[k*32 + 16 + c]; }
    double mu  = S * (1.0/(2.0*EE));
    double var = Q * (1.0/(2.0*EE)) - mu*mu;
    float sc = rsqrtf((float)var + 1e-5f);
    float A = sc * g[c];
    sA[c] = A; sB[c] = bt[c] - (float)mu * A;
  }
  __syncthreads();

  int t = blockIdx.x*256 + threadIdx.x;
  bool val = (t < EE);
  float lsum = 0.0f;
  if (val){
    int s = ei[t], d = ei[EE+t];
    float4 xs[4], xd[4];
    const float4* p;
    p = (const float4*)(x + (size_t)s*CC); xs[0]=p[0]; xs[1]=p[1]; xs[2]=p[2]; xs[3]=p[3];
    p = (const float4*)(x + (size_t)d*CC); xd[0]=p[0]; xd[1]=p[1]; xd[2]=p[2]; xd[3]=p[3];
    float fo[16];
#pragma unroll
    for (int c=0;c<CC;c++){
      const float4* wr = (const float4*)(sW + c*32);
      float f = sb16[c], g_ = sb16[c];
#pragma unroll
      for (int q=0;q<4;q++){ float4 w = wr[q];   f = fma4(w, xs[q], f);  g_ = fma4(w, xd[q], g_); }
#pragma unroll
      for (int q=0;q<4;q++){ float4 w = wr[4+q]; f = fma4(w, xd[q], f);  g_ = fma4(w, xs[q], g_); }
      float efv = lrelu(fmaf(sA[c], f,  sB[c]));
      float ebv = lrelu(fmaf(sA[c], g_, sB[c]));
      fo[c] = 0.5f*(efv + ebv);
      float dlt = efv - ebv;
      lsum = fmaf(dlt, dlt, lsum);
    }
    float4* po = (float4*)(out + (size_t)t*CC);
    po[0]=make_float4(fo[0],fo[1],fo[2],fo[3]);
    po[1]=make_float4(fo[4],fo[5],fo[6],fo[7]);
    po[2]=make_float4(fo[8],fo[9],fo[10],fo[11]);
    po[3]=make_float4(fo[12],fo[13],fo[14],fo[15]);
  }
  lsum = waveSum(lsum);
  int lane = threadIdx.x & 63, w = threadIdx.x >> 6;
  if (lane == 0) sl[w] = lsum;
  __syncthreads();
  if (threadIdx.x == 0)
    unsafeAtomicAdd(&loss[blockIdx.x & (NB-1)], (double)(sl[0]+sl[1]+sl[2]+sl[3]));
}

__global__ void k_final3(float* __restrict__ out, const double* __restrict__ loss)
{
  double s = 0.0;
#pragma unroll
  for (int k=0;k<NB;k++) s += loss[k];
  out[(size_t)EE*CC] = (float)(s * (1.0/((double)EE*CC)));
}

// ---------- host ----------
extern "C" void kernel_launch(void* const* d_in, const int* in_sizes, int n_in,
                              void* d_out, int out_size, void* d_ws, size_t ws_size,
                              hipStream_t stream)
{
  (void)in_sizes; (void)n_in; (void)out_size; (void)ws_size;
  const float* ef  = (const float*)d_in[0];
  const int*   ei  = (const int*)d_in[1];
  // d_in[2] = angles (unused by reference forward)
  const float* Wn  = (const float*)d_in[3];
  const float* bn  = (const float*)d_in[4];
  const float* gn  = (const float*)d_in[5];
  const float* btn = (const float*)d_in[6];
  const float* We  = (const float*)d_in[7];
  const float* be  = (const float*)d_in[8];
  const float* ge  = (const float*)d_in[9];
  const float* bte = (const float*)d_in[10];
  float* out = (float*)d_out;
  char* ws = (char*)d_ws;

  size_t off = 0;
  auto alloc = [&](size_t bytes)->size_t{
    size_t r = off; off = (off + bytes + 255) & ~(size_t)255; return r;
  };
  size_t o_xa     = alloc((size_t)NN*CC*4);
  size_t o_xb     = alloc((size_t)NN*CC*4);
  size_t o_mh     = alloc((size_t)EE*8*4);      // fp16 m_hat: E x 16 ch = E x 8 uints
  size_t o_cdst   = alloc((size_t)NN*4);
  size_t o_call   = alloc((size_t)NN*4);
  size_t o_rp     = alloc((size_t)(NN+1)*4);
  size_t o_rpall  = alloc((size_t)(NN+1)*4);
  size_t o_cur    = alloc((size_t)NN*4);
  size_t o_curall = alloc((size_t)NN*4);
  size_t o_sd     = alloc((size_t)EE*8);
  size_t o_listall= alloc((size_t)2*EE*4);
  size_t o_bsum   = alloc(512);
  size_t o_bsum2  = alloc(512);
  size_t o_boff   = alloc(512);
  size_t o_boff2  = alloc(512);
  // stats: 17 layer-slots * NB buckets * 32 doubles, + NB loss doubles
  size_t o_stats  = alloc((size_t)(17*NB*32 + NB)*8);
  size_t o_invdeg = alloc((size_t)NN*4);

  float*  x_a     = (float*)(ws + o_xa);
  float*  x_b     = (float*)(ws + o_xb);
  uint*   m_h     = (uint*)(ws + o_mh);
  int*    cdst    = (int*)(ws + o_cdst);
  int*    call_   = (int*)(ws + o_call);
  int*    rp      = (int*)(ws + o_rp);
  int*    rp_all  = (int*)(ws + o_rpall);
  int*    cur     = (int*)(ws + o_cur);
  int*    cur_all = (int*)(ws + o_curall);
  int2*   sd      = (int2*)(ws + o_sd);
  int*    list_all= (int*)(ws + o_listall);
  int*    bsum    = (int*)(ws + o_bsum);
  int*    bsum2   = (int*)(ws + o_bsum2);
  int*    boff    = (int*)(ws + o_boff);
  int*    boff2   = (int*)(ws + o_boff2);
  double* stats   = (double*)(ws + o_stats);
  double* lossd   = stats + (size_t)17*NB*32;
  float*  invdeg  = (float*)(ws + o_invdeg);

  const int GB_E  = (EE + 255)/256;        // 1563
  const int GB_E2 = (EE/2 + 255)/256;      // 782
  const int GB_NC = (NN*CC + 255)/256;     // 6250
  const int GB_N8 = (NN*8 + 255)/256;      // 3125
  const int NSEG  = (NN + 1023)/1024;      // 98

  hipMemsetAsync(cdst, 0, (size_t)NN*4, stream);
  hipMemsetAsync(call_, 0, (size_t)NN*4, stream);
  hipMemsetAsync(stats, 0, (size_t)(17*NB*32 + NB)*8, stream);

  k_count<<<GB_E, 256, 0, stream>>>(ei, cdst, call_);
  k_scan1<<<NSEG, 256, 0, stream>>>(cdst, rp, bsum, call_, rp_all, bsum2, NN);
  k_scan2<<<1, 256, 0, stream>>>(bsum, boff, bsum2, boff2, NSEG);
  k_scan3<<<NSEG, 256, 0, stream>>>(rp, cur, boff, EE, rp_all, cur_all, boff2, 2*EE, NN);
  k_fill<<<GB_E, 256, 0, stream>>>(ei, cur, sd, cur_all, list_all);
  k_gather0<<<GB_NC, 256, 0, stream>>>(ef, rp_all, list_all, rp, x_a, invdeg);

  const float* xc = x_a;
  float* xn = x_b;
  for (int l = 0; l < LL; ++l){
    double* st = stats + (size_t)l*NB*32;
    const float* Wl = Wn + (size_t)l*CC*2*CC;
    const float* bl = bn + (size_t)l*CC;
    k_edge<<<GB_E2, 256, 0, stream>>>(xc, sd, Wl, bl, m_h, st);
    k_node<<<GB_N8, 256, 0, stream>>>(m_h, rp, invdeg, st,
                                      gn + (size_t)l*CC, btn + (size_t)l*CC, xn);
    float* tmp = (float*)xc; xc = xn; xn = tmp;
  }

  double* stF = stats + (size_t)16*NB*32;
  k_final1<<<GB_E, 256, 0, stream>>>(xc, ei, We, be, stF);
  k_final2<<<GB_E, 256, 0, stream>>>(xc, ei, We, be, stF, ge, bte, out, lossd);
  k_final3<<<1, 1, 0, stream>>>(out, lossd);
}